// Round 1
// baseline (267.637 us; speedup 1.0000x reference)
//
#include <hip/hip_runtime.h>
#include <stdint.h>

#define Bn 4
#define Cn 256
#define On 256
#define Gn 64
#define Hn 64
#define Wn 64
#define HWn 4096
#define EPSf 1e-5f

// workspace byte offsets (all 16B-aligned)
#define WS_XT    0u           // x transposed NHWC f32: 16777216 B
#define WS_OFF   16777216u    // offsets (B,18,H,W) f32: 1179648 B
#define WS_T     17956864u    // t NHWC bf16: 8388608 B
#define WS_PWB   26345472u    // pw bf16: 131072 B
#define WS_DWT   26476544u    // dw transposed [k][c] f32: 9216 B
#define WS_OSC   26485760u    // off bn scale (18)
#define WS_OSH   26485888u    // off bn shift (18)
#define WS_BSC   26486016u    // out bn scale (256)
#define WS_BSH   26487040u    // out bn shift (256)
#define WS_WT    26488064u    // off_w transposed [g][ty][tx][ch]: 41472 B
// total ~26.6 MB

typedef __attribute__((ext_vector_type(8))) short short8;
typedef __attribute__((ext_vector_type(4))) float f4;

__device__ __forceinline__ unsigned int bfround(float f) {
    unsigned int u = __float_as_uint(f);
    u += 0x7FFFu + ((u >> 16) & 1u);
    return u >> 16;  // RNE bf16 in low 16 bits
}

// ---------------- prep: transpose x to NHWC + small tables ----------------
__global__ void k_prep(const float* __restrict__ x, const float* __restrict__ off_w,
                       const float* __restrict__ og, const float* __restrict__ ob,
                       const float* __restrict__ om, const float* __restrict__ ov,
                       const float* __restrict__ dw_w, const float* __restrict__ pw_w,
                       const float* __restrict__ bg, const float* __restrict__ bb,
                       const float* __restrict__ bm, const float* __restrict__ bv,
                       char* __restrict__ ws)
{
    int tid = threadIdx.x;
    if (blockIdx.x < 1024) {
        // 64x64 tile transpose of (C=256 x HW=4096) per batch
        float* xt = (float*)(ws + WS_XT);
        __shared__ float tile[64][65];
        int bi = blockIdx.x;
        int pt = bi & 63, ct = (bi >> 6) & 3, b = bi >> 8;
        int p0 = pt * 64, c0 = ct * 64;
        const float* xb = x + (size_t)b * Cn * HWn;
        #pragma unroll
        for (int it = 0; it < 16; ++it) {
            int idx = it * 256 + tid;
            int ci = idx >> 6, pi = idx & 63;
            tile[ci][pi] = xb[(size_t)(c0 + ci) * HWn + p0 + pi];
        }
        __syncthreads();
        float* xtb = xt + (size_t)b * HWn * Cn;
        #pragma unroll
        for (int it = 0; it < 16; ++it) {
            int idx = it * 256 + tid;
            int pi = idx >> 6, ci = idx & 63;
            xtb[(size_t)(p0 + pi) * Cn + c0 + ci] = tile[ci][pi];
        }
    } else {
        unsigned short* pwb = (unsigned short*)(ws + WS_PWB);
        float* dwt = (float*)(ws + WS_DWT);
        float* osc = (float*)(ws + WS_OSC);
        float* osh = (float*)(ws + WS_OSH);
        float* bsc = (float*)(ws + WS_BSC);
        float* bsh = (float*)(ws + WS_BSH);
        float* wT  = (float*)(ws + WS_WT);
        if (tid < 18) {
            float s = og[tid] * rsqrtf(ov[tid] + EPSf);
            osc[tid] = s;
            osh[tid] = ob[tid] - om[tid] * s;
        }
        {
            float s = bg[tid] * rsqrtf(bv[tid] + EPSf);
            bsc[tid] = s;
            bsh[tid] = bb[tid] - bm[tid] * s;
        }
        for (int idx = tid; idx < 2304; idx += 256) {
            int k = idx >> 8, c = idx & 255;
            dwt[idx] = dw_w[c * 9 + k];        // dwt[k][c]
        }
        for (int idx = tid; idx < 10368; idx += 256) {
            int ch = idx % 18; int r = idx / 18;
            int tx = r % 3; r /= 3; int ty = r % 3; int g = r / 3;
            wT[idx] = off_w[((ch * 64 + g) * 3 + ty) * 3 + tx];  // wT[g][ty][tx][ch]
        }
        for (int idx = tid; idx < 65536; idx += 256)
            pwb[idx] = (unsigned short)bfround(pw_w[idx]);
    }
}

// ---------------- offset conv (G=64 -> 18, 3x3, pad 1) + BN + ReLU ----------------
__global__ void k_off(const float* __restrict__ gf, char* __restrict__ ws)
{
    const float* wT  = (const float*)(ws + WS_WT);
    const float* osc = (const float*)(ws + WS_OSC);
    const float* osh = (const float*)(ws + WS_OSH);
    float* off = (float*)(ws + WS_OFF);
    int h = blockIdx.x, b = blockIdx.y;
    int w = threadIdx.x & 63;
    int chb = (threadIdx.x >> 6) * 6;   // wave -> 6-channel group (3 waves x 6 = 18)
    float acc[6] = {0.f, 0.f, 0.f, 0.f, 0.f, 0.f};
    const float* gfb = gf + (size_t)b * Gn * HWn;
    for (int g = 0; g < Gn; ++g) {
        const float* gfg = gfb + (size_t)g * HWn;
        #pragma unroll
        for (int ty = 0; ty < 3; ++ty) {
            int y = h + ty - 1;
            if ((unsigned)y < 64u) {
                const float* row = gfg + y * Wn;
                float v1 = row[w];
                float v0 = (w > 0) ? row[w - 1] : 0.f;
                float v2 = (w < 63) ? row[w + 1] : 0.f;
                // wT[g][ty][tx][ch]: ch-base even -> 8B-aligned float2 loads
                const float2* wp2 = (const float2*)(wT + (g * 3 + ty) * 54 + chb);
                float2 a0 = wp2[0],  a1 = wp2[1],  a2 = wp2[2];   // tx=0
                float2 b0 = wp2[9],  b1 = wp2[10], b2 = wp2[11];  // tx=1
                float2 c0 = wp2[18], c1 = wp2[19], c2 = wp2[20];  // tx=2
                acc[0] += a0.x * v0 + b0.x * v1 + c0.x * v2;
                acc[1] += a0.y * v0 + b0.y * v1 + c0.y * v2;
                acc[2] += a1.x * v0 + b1.x * v1 + c1.x * v2;
                acc[3] += a1.y * v0 + b1.y * v1 + c1.y * v2;
                acc[4] += a2.x * v0 + b2.x * v1 + c2.x * v2;
                acc[5] += a2.y * v0 + b2.y * v1 + c2.y * v2;
            }
        }
    }
    #pragma unroll
    for (int j = 0; j < 6; ++j) {
        int ch = chb + j;
        float v = acc[j] * osc[ch] + osh[ch];
        v = v > 0.f ? v : 0.f;
        off[((size_t)(b * 18 + ch) * Hn + h) * Wn + w] = v;
    }
}

// ---------------- deformable bilinear sample + depthwise -> t (NHWC bf16) ----------------
__global__ void k_samp(char* __restrict__ ws)
{
    const float* xt  = (const float*)(ws + WS_XT);
    const float* off = (const float*)(ws + WS_OFF);
    const float* dwt = (const float*)(ws + WS_DWT);
    unsigned short* t = (unsigned short*)(ws + WS_T);
    __shared__ float smeta[64 * 9 * 8];   // per (w,k): 4 weights + 4 byte-offsets
    int h = blockIdx.x, b = blockIdx.y;
    int tid = threadIdx.x;

    for (int e = tid; e < 576; e += 256) {
        int w = e / 9, k = e % 9;
        int kyi = k / 3, kxi = k % 3;
        float dy = off[((size_t)(b * 18 + 2 * k) * Hn + h) * Wn + w];
        float dx = off[((size_t)(b * 18 + 2 * k + 1) * Hn + h) * Wn + w];
        float gy = (float)(h + (kyi - 1) * 2) + dy;
        float gx = (float)(w + (kxi - 1) * 2) + dx;
        float fy = floorf(gy), fx = floorf(gx);
        float wy = gy - fy, wx = gx - fx;
        int y0 = (int)fy, x0 = (int)fx;
        int y1 = y0 + 1, x1 = x0 + 1;
        float m00 = ((unsigned)y0 < 64u && (unsigned)x0 < 64u) ? 1.f : 0.f;
        float m01 = ((unsigned)y0 < 64u && (unsigned)x1 < 64u) ? 1.f : 0.f;
        float m10 = ((unsigned)y1 < 64u && (unsigned)x0 < 64u) ? 1.f : 0.f;
        float m11 = ((unsigned)y1 < 64u && (unsigned)x1 < 64u) ? 1.f : 0.f;
        int y0c = min(max(y0, 0), 63), y1c = min(max(y1, 0), 63);
        int x0c = min(max(x0, 0), 63), x1c = min(max(x1, 0), 63);
        float4 mw;
        mw.x = (1.f - wy) * (1.f - wx) * m00;
        mw.y = (1.f - wy) * wx * m01;
        mw.z = wy * (1.f - wx) * m10;
        mw.w = wy * wx * m11;
        float4 mo;
        mo.x = __int_as_float((y0c * 64 + x0c) << 10);  // *256 ch *4 B
        mo.y = __int_as_float((y0c * 64 + x1c) << 10);
        mo.z = __int_as_float((y1c * 64 + x0c) << 10);
        mo.w = __int_as_float((y1c * 64 + x1c) << 10);
        float4* s4w = (float4*)smeta;
        s4w[e * 2] = mw;
        s4w[e * 2 + 1] = mo;
    }
    __syncthreads();

    int lane = tid & 63, wave = tid >> 6;
    int c0 = lane * 4;
    float4 dwk[9];
    #pragma unroll
    for (int k = 0; k < 9; ++k)
        dwk[k] = *(const float4*)(dwt + k * 256 + c0);
    const char* xb = (const char*)(xt + (size_t)b * HWn * Cn);
    int laneByte = lane * 16;
    const float4* s4 = (const float4*)smeta;

    for (int w = wave; w < 64; w += 4) {
        float ax = 0.f, ay = 0.f, az = 0.f, aw = 0.f;
        #pragma unroll
        for (int k = 0; k < 9; ++k) {
            float4 mw = s4[(w * 9 + k) * 2];
            float4 mo = s4[(w * 9 + k) * 2 + 1];
            float4 v00 = *(const float4*)(xb + __float_as_int(mo.x) + laneByte);
            float4 v01 = *(const float4*)(xb + __float_as_int(mo.y) + laneByte);
            float4 v10 = *(const float4*)(xb + __float_as_int(mo.z) + laneByte);
            float4 v11 = *(const float4*)(xb + __float_as_int(mo.w) + laneByte);
            float bx = mw.x * v00.x + mw.y * v01.x + mw.z * v10.x + mw.w * v11.x;
            float by = mw.x * v00.y + mw.y * v01.y + mw.z * v10.y + mw.w * v11.y;
            float bz = mw.x * v00.z + mw.y * v01.z + mw.z * v10.z + mw.w * v11.z;
            float bw = mw.x * v00.w + mw.y * v01.w + mw.z * v10.w + mw.w * v11.w;
            ax += bx * dwk[k].x;
            ay += by * dwk[k].y;
            az += bz * dwk[k].z;
            aw += bw * dwk[k].w;
        }
        uint2 pk;
        pk.x = bfround(ax) | (bfround(ay) << 16);
        pk.y = bfround(az) | (bfround(aw) << 16);
        *(uint2*)(t + ((size_t)(b * HWn + h * 64 + w) * Cn + c0)) = pk;
    }
}

// ---------------- pointwise 1x1 (bf16 MFMA) + BN + ReLU ----------------
__global__ void k_pw(float* __restrict__ out, const char* __restrict__ ws)
{
    const unsigned short* pwb = (const unsigned short*)(ws + WS_PWB);
    const unsigned short* t   = (const unsigned short*)(ws + WS_T);
    const float* bsc = (const float*)(ws + WS_BSC);
    const float* bsh = (const float*)(ws + WS_BSH);
    int tid = threadIdx.x;
    int lane = tid & 63, wave = tid >> 6;
    int bz = blockIdx.z;
    int m0 = blockIdx.y * 64;                  // O-dim tile
    int n0 = blockIdx.x * 256 + wave * 64;     // HW-dim tile (per wave)
    int row = lane & 15, quad = lane >> 4;

    f4 acc[4][4];
    #pragma unroll
    for (int i = 0; i < 4; ++i)
        #pragma unroll
        for (int j = 0; j < 4; ++j)
            acc[i][j] = (f4){0.f, 0.f, 0.f, 0.f};

    const unsigned short* tb = t + (size_t)bz * HWn * Cn;
    #pragma unroll 2
    for (int kq = 0; kq < 8; ++kq) {
        int kk = kq * 32 + quad * 8;
        short8 a[4], bf[4];
        #pragma unroll
        for (int mt = 0; mt < 4; ++mt)
            a[mt] = *(const short8*)(pwb + (size_t)(m0 + mt * 16 + row) * Cn + kk);
        #pragma unroll
        for (int nt = 0; nt < 4; ++nt)
            bf[nt] = *(const short8*)(tb + (size_t)(n0 + nt * 16 + row) * Cn + kk);
        #pragma unroll
        for (int mt = 0; mt < 4; ++mt)
            #pragma unroll
            for (int nt = 0; nt < 4; ++nt)
                acc[mt][nt] = __builtin_amdgcn_mfma_f32_16x16x32_bf16(a[mt], bf[nt], acc[mt][nt], 0, 0, 0);
    }

    #pragma unroll
    for (int mt = 0; mt < 4; ++mt) {
        #pragma unroll
        for (int r = 0; r < 4; ++r) {
            int o = m0 + mt * 16 + quad * 4 + r;
            float sc = bsc[o], sh = bsh[o];
            #pragma unroll
            for (int nt = 0; nt < 4; ++nt) {
                float v = acc[mt][nt][r] * sc + sh;
                v = v > 0.f ? v : 0.f;
                out[(size_t)(bz * On + o) * HWn + n0 + nt * 16 + row] = v;
            }
        }
    }
}

extern "C" void kernel_launch(void* const* d_in, const int* in_sizes, int n_in,
                              void* d_out, int out_size, void* d_ws, size_t ws_size,
                              hipStream_t stream)
{
    const float* x     = (const float*)d_in[0];
    const float* gf    = (const float*)d_in[1];
    const float* off_w = (const float*)d_in[2];
    const float* og    = (const float*)d_in[3];
    const float* ob    = (const float*)d_in[4];
    const float* om    = (const float*)d_in[5];
    const float* ov    = (const float*)d_in[6];
    const float* dw_w  = (const float*)d_in[7];
    const float* pw_w  = (const float*)d_in[8];
    const float* bg    = (const float*)d_in[9];
    const float* bb    = (const float*)d_in[10];
    const float* bm    = (const float*)d_in[11];
    const float* bv    = (const float*)d_in[12];
    float* out = (float*)d_out;
    char* ws = (char*)d_ws;

    hipLaunchKernelGGL(k_prep, dim3(1025), dim3(256), 0, stream,
                       x, off_w, og, ob, om, ov, dw_w, pw_w, bg, bb, bm, bv, ws);
    hipLaunchKernelGGL(k_off, dim3(Hn, Bn), dim3(192), 0, stream, gf, ws);
    hipLaunchKernelGGL(k_samp, dim3(Hn, Bn), dim3(256), 0, stream, ws);
    hipLaunchKernelGGL(k_pw, dim3(16, 4, Bn), dim3(256), 0, stream, out, ws);
}

// Round 2
// 243.669 us; speedup vs baseline: 1.0984x; 1.0984x over previous
//
#include <hip/hip_runtime.h>
#include <stdint.h>

#define Bn 4
#define Cn 256
#define On 256
#define Gn 64
#define Hn 64
#define Wn 64
#define HWn 4096
#define EPSf 1e-5f

// workspace byte offsets (16B-aligned)
#define WS_XT    0u               // x NHWC bf16: 8388608
#define WS_OFF   8388608u         // off [b][pos][18] f32: 1179648
#define WS_T     9568256u         // t NHWC bf16: 8388608
#define WS_PWB   17956864u        // pw bf16 [o][c]: 131072
#define WS_DWT   18087936u        // dw [k][c] f32: 9216
#define WS_OSC   18097152u
#define WS_OSH   18097280u
#define WS_BSC   18097408u
#define WS_BSH   18098432u
#define WS_WT    18099456u        // off_w [g][ty][56] f32 (tx*18+ch in row): 43008

typedef __attribute__((ext_vector_type(8))) short short8;
typedef __attribute__((ext_vector_type(4))) float f4;

__device__ __forceinline__ unsigned int bfround(float f) {
    unsigned int u = __float_as_uint(f);
    u += 0x7FFFu + ((u >> 16) & 1u);
    return u >> 16;
}
__device__ __forceinline__ float blo(unsigned u) { return __uint_as_float(u << 16); }
__device__ __forceinline__ float bhi(unsigned u) { return __uint_as_float(u & 0xFFFF0000u); }

// ---------------- tables (1 tiny block) ----------------
__global__ void k_tables(const float* __restrict__ off_w,
                         const float* __restrict__ og, const float* __restrict__ ob,
                         const float* __restrict__ om, const float* __restrict__ ov,
                         const float* __restrict__ dw_w, const float* __restrict__ pw_w,
                         const float* __restrict__ bg, const float* __restrict__ bb,
                         const float* __restrict__ bm, const float* __restrict__ bv,
                         char* __restrict__ ws)
{
    int tid = threadIdx.x;
    unsigned short* pwb = (unsigned short*)(ws + WS_PWB);
    float* dwt = (float*)(ws + WS_DWT);
    float* osc = (float*)(ws + WS_OSC);
    float* osh = (float*)(ws + WS_OSH);
    float* bsc = (float*)(ws + WS_BSC);
    float* bsh = (float*)(ws + WS_BSH);
    float* wT  = (float*)(ws + WS_WT);
    if (tid < 18) {
        float s = og[tid] * rsqrtf(ov[tid] + EPSf);
        osc[tid] = s;
        osh[tid] = ob[tid] - om[tid] * s;
    }
    {
        float s = bg[tid] * rsqrtf(bv[tid] + EPSf);
        bsc[tid] = s;
        bsh[tid] = bb[tid] - bm[tid] * s;
    }
    for (int idx = tid; idx < 2304; idx += 256) {
        int k = idx >> 8, c = idx & 255;
        dwt[idx] = dw_w[c * 9 + k];                     // dwt[k][c]
    }
    for (int i = tid; i < 10368; i += 256) {
        int ch = i % 18; int r = i / 18;
        int tx = r % 3; r /= 3; int ty = r % 3; int g = r / 3;
        wT[(g * 3 + ty) * 56 + tx * 18 + ch] = off_w[((ch * 64 + g) * 3 + ty) * 3 + tx];
    }
    for (int idx = tid; idx < 65536; idx += 256)
        pwb[idx] = (unsigned short)bfround(pw_w[idx]);
}

// ---------------- transpose x NCHW f32 -> NHWC bf16 ----------------
__global__ void k_tr(const float* __restrict__ x, char* __restrict__ ws)
{
    unsigned short* xt = (unsigned short*)(ws + WS_XT);
    __shared__ float tile[64 * 65];
    int tid = threadIdx.x, bi = blockIdx.x;
    int pt = bi & 63, ct = (bi >> 6) & 3, b = bi >> 8;
    int p0 = pt * 64, c0 = ct * 64;
    const float4* x4 = (const float4*)(x + (size_t)b * Cn * HWn);
    #pragma unroll
    for (int it = 0; it < 4; ++it) {
        int v = it * 256 + tid;
        int ci = v >> 4, pj = v & 15;
        float4 f = x4[(size_t)(c0 + ci) * 1024 + (p0 >> 2) + pj];
        tile[ci * 65 + pj * 4 + 0] = f.x;
        tile[ci * 65 + pj * 4 + 1] = f.y;
        tile[ci * 65 + pj * 4 + 2] = f.z;
        tile[ci * 65 + pj * 4 + 3] = f.w;
    }
    __syncthreads();
    unsigned short* xtb = xt + (size_t)b * HWn * Cn;
    #pragma unroll
    for (int it = 0; it < 2; ++it) {
        int u = it * 256 + tid;
        int pi = u >> 3, cj = u & 7;
        float f[8];
        #pragma unroll
        for (int j = 0; j < 8; ++j)
            f[j] = tile[(cj * 8 + j) * 65 + pi];
        uint4 pk;
        pk.x = bfround(f[0]) | (bfround(f[1]) << 16);
        pk.y = bfround(f[2]) | (bfround(f[3]) << 16);
        pk.z = bfround(f[4]) | (bfround(f[5]) << 16);
        pk.w = bfround(f[6]) | (bfround(f[7]) << 16);
        *(uint4*)(xtb + (size_t)(p0 + pi) * Cn + c0 + cj * 8) = pk;
    }
}

// ---------------- offset conv (G=64->18, 3x3, pad1) + BN + ReLU ----------------
// block (h,b), 512 threads = 8 waves; wave wv handles g in [wv*8, wv*8+8)
__global__ void k_off(const float* __restrict__ gf, char* __restrict__ ws)
{
    const float* __restrict__ wT  = (const float*)(ws + WS_WT);
    const float* __restrict__ osc = (const float*)(ws + WS_OSC);
    const float* __restrict__ osh = (const float*)(ws + WS_OSH);
    float* __restrict__ off = (float*)(ws + WS_OFF);
    __shared__ float sgf[3 * 64 * 72];        // [ty][g][72]; data at [4..67], halos [3],[68]
    __shared__ float sred[8 * 18 * 64];       // [wv][ch][w]
    int h = blockIdx.x, b = blockIdx.y;
    int tid = threadIdx.x;
    int lane = tid & 63;

    // stage gf rows h-1..h+1 for all 64 g (zero-padded)
    const float4* gf4 = (const float4*)gf;
    #pragma unroll
    for (int i = 0; i < 6; ++i) {
        int idx = i * 512 + tid;              // over 3072 float4
        int r = idx >> 4, pj = idx & 15;      // r = ty*64+g
        int ty = r >> 6, g = r & 63;
        int y = h + ty - 1;
        float4 v = {0.f, 0.f, 0.f, 0.f};
        if ((unsigned)y < 64u)
            v = gf4[((size_t)(b * 64 + g) * 64 + y) * 16 + pj];
        *(float4*)(&sgf[r * 72 + 4 + pj * 4]) = v;
    }
    if (tid < 192) {
        sgf[tid * 72 + 3] = 0.f;
        sgf[tid * 72 + 68] = 0.f;
    }
    __syncthreads();

    int wvU = __builtin_amdgcn_readfirstlane(tid >> 6);   // uniform wave id
    float acc[18];
    #pragma unroll
    for (int ch = 0; ch < 18; ++ch) acc[ch] = 0.f;

    for (int gi = 0; gi < 8; ++gi) {
        int g = wvU * 8 + gi;
        #pragma unroll
        for (int ty = 0; ty < 3; ++ty) {
            const float* row = &sgf[(ty * 64 + g) * 72];
            float v0 = row[3 + lane];
            float v1 = row[4 + lane];
            float v2 = row[5 + lane];
            const float* wrow = wT + (g * 3 + ty) * 56;   // uniform address -> s_load
            #pragma unroll
            for (int ch = 0; ch < 18; ++ch)
                acc[ch] += wrow[ch] * v0 + wrow[18 + ch] * v1 + wrow[36 + ch] * v2;
        }
    }
    #pragma unroll
    for (int ch = 0; ch < 18; ++ch)
        sred[(wvU * 18 + ch) * 64 + lane] = acc[ch];
    __syncthreads();

    float* ob = off + (size_t)(b * HWn + h * 64) * 18;
    for (int idx = tid; idx < 1152; idx += 512) {
        int w = idx / 18, ch = idx - w * 18;
        float v = 0.f;
        #pragma unroll
        for (int wv = 0; wv < 8; ++wv)
            v += sred[(wv * 18 + ch) * 64 + w];
        v = v * osc[ch] + osh[ch];
        ob[idx] = v > 0.f ? v : 0.f;
    }
}

// ---------------- deformable bilinear + depthwise -> t NHWC bf16 ----------------
// block (h,b), 512 threads = 8 waves; wave handles 2 positions/iter (32 lanes x 8ch each)
__global__ void k_samp(char* __restrict__ ws)
{
    const unsigned short* __restrict__ xt = (const unsigned short*)(ws + WS_XT);
    const float* __restrict__ off = (const float*)(ws + WS_OFF);
    const float* __restrict__ dwt = (const float*)(ws + WS_DWT);
    unsigned short* __restrict__ t = (unsigned short*)(ws + WS_T);
    __shared__ float smeta[576 * 8];          // [(k*64+w)]: 4 weights + 4 byte-offsets
    int h = blockIdx.x, b = blockIdx.y;
    int tid = threadIdx.x;

    for (int e = tid; e < 576; e += 512) {
        int k = e >> 6, w = e & 63;
        int kyi = k / 3, kxi = k - kyi * 3;
        const float* op = off + ((size_t)(b * HWn + h * 64 + w)) * 18 + 2 * k;
        float dy = op[0], dx = op[1];
        float gy = (float)(h + (kyi - 1) * 2) + dy;
        float gx = (float)(w + (kxi - 1) * 2) + dx;
        float fy = floorf(gy), fx = floorf(gx);
        float wy = gy - fy, wx = gx - fx;
        int y0 = (int)fy, x0 = (int)fx;
        int y1 = y0 + 1, x1 = x0 + 1;
        float m00 = ((unsigned)y0 < 64u && (unsigned)x0 < 64u) ? 1.f : 0.f;
        float m01 = ((unsigned)y0 < 64u && (unsigned)x1 < 64u) ? 1.f : 0.f;
        float m10 = ((unsigned)y1 < 64u && (unsigned)x0 < 64u) ? 1.f : 0.f;
        float m11 = ((unsigned)y1 < 64u && (unsigned)x1 < 64u) ? 1.f : 0.f;
        int y0c = min(max(y0, 0), 63), y1c = min(max(y1, 0), 63);
        int x0c = min(max(x0, 0), 63), x1c = min(max(x1, 0), 63);
        float4 mw;
        mw.x = (1.f - wy) * (1.f - wx) * m00;
        mw.y = (1.f - wy) * wx * m01;
        mw.z = wy * (1.f - wx) * m10;
        mw.w = wy * wx * m11;
        float4 mo;
        mo.x = __int_as_float((y0c * 64 + x0c) << 9);   // *256ch *2B
        mo.y = __int_as_float((y0c * 64 + x1c) << 9);
        mo.z = __int_as_float((y1c * 64 + x0c) << 9);
        mo.w = __int_as_float((y1c * 64 + x1c) << 9);
        float4* s4w = (float4*)smeta;
        s4w[(k * 64 + w) * 2] = mw;
        s4w[(k * 64 + w) * 2 + 1] = mo;
    }

    int lane = tid & 63, wave = tid >> 6;
    int half = lane >> 5, c8 = lane & 31;
    int c0 = c8 * 8;
    float dwr[9][8];
    #pragma unroll
    for (int k = 0; k < 9; ++k) {
        *(float4*)&dwr[k][0] = *(const float4*)(dwt + k * 256 + c0);
        *(float4*)&dwr[k][4] = *(const float4*)(dwt + k * 256 + c0 + 4);
    }
    __syncthreads();

    const char* xb = (const char*)(xt + (size_t)b * HWn * Cn);
    int laneByte = c8 * 16;
    const float4* s4 = (const float4*)smeta;

    for (int iter = 0; iter < 4; ++iter) {
        int w = iter * 16 + wave * 2 + half;
        float acc[8];
        #pragma unroll
        for (int j = 0; j < 8; ++j) acc[j] = 0.f;
        #pragma unroll
        for (int k = 0; k < 9; ++k) {
            float4 mw = s4[(k * 64 + w) * 2];
            float4 mo = s4[(k * 64 + w) * 2 + 1];
            uint4 qA = *(const uint4*)(xb + __float_as_int(mo.x) + laneByte);
            uint4 qB = *(const uint4*)(xb + __float_as_int(mo.y) + laneByte);
            uint4 qC = *(const uint4*)(xb + __float_as_int(mo.z) + laneByte);
            uint4 qD = *(const uint4*)(xb + __float_as_int(mo.w) + laneByte);
            const unsigned* uA = (const unsigned*)&qA;
            const unsigned* uB = (const unsigned*)&qB;
            const unsigned* uC = (const unsigned*)&qC;
            const unsigned* uD = (const unsigned*)&qD;
            #pragma unroll
            for (int j = 0; j < 4; ++j) {
                float sl = mw.x * blo(uA[j]) + mw.y * blo(uB[j]) + mw.z * blo(uC[j]) + mw.w * blo(uD[j]);
                float sh = mw.x * bhi(uA[j]) + mw.y * bhi(uB[j]) + mw.z * bhi(uC[j]) + mw.w * bhi(uD[j]);
                acc[2 * j]     += sl * dwr[k][2 * j];
                acc[2 * j + 1] += sh * dwr[k][2 * j + 1];
            }
        }
        uint4 pk;
        pk.x = bfround(acc[0]) | (bfround(acc[1]) << 16);
        pk.y = bfround(acc[2]) | (bfround(acc[3]) << 16);
        pk.z = bfround(acc[4]) | (bfround(acc[5]) << 16);
        pk.w = bfround(acc[6]) | (bfround(acc[7]) << 16);
        *(uint4*)(t + (size_t)(b * HWn + h * 64 + w) * Cn + c0) = pk;
    }
}

// ---------------- pointwise 1x1 bf16 MFMA + BN + ReLU ----------------
// grid (16,8,4): n-tile 256/block (wave 64), m-tile 32
__global__ void k_pw(float* __restrict__ out, const char* __restrict__ ws)
{
    const unsigned short* __restrict__ pwb = (const unsigned short*)(ws + WS_PWB);
    const unsigned short* __restrict__ t   = (const unsigned short*)(ws + WS_T);
    const float* __restrict__ bsc = (const float*)(ws + WS_BSC);
    const float* __restrict__ bsh = (const float*)(ws + WS_BSH);
    int tid = threadIdx.x;
    int lane = tid & 63, wave = tid >> 6;
    int bz = blockIdx.z;
    int m0 = blockIdx.y * 32;
    int n0 = blockIdx.x * 256 + wave * 64;
    int row = lane & 15, quad = lane >> 4;

    f4 acc[2][4];
    #pragma unroll
    for (int i = 0; i < 2; ++i)
        #pragma unroll
        for (int j = 0; j < 4; ++j)
            acc[i][j] = (f4){0.f, 0.f, 0.f, 0.f};

    const unsigned short* tb = t + (size_t)bz * HWn * Cn;
    #pragma unroll 2
    for (int kq = 0; kq < 8; ++kq) {
        int kk = kq * 32 + quad * 8;
        short8 a[2], bf[4];
        #pragma unroll
        for (int mt = 0; mt < 2; ++mt)
            a[mt] = *(const short8*)(pwb + (size_t)(m0 + mt * 16 + row) * Cn + kk);
        #pragma unroll
        for (int nt = 0; nt < 4; ++nt)
            bf[nt] = *(const short8*)(tb + (size_t)(n0 + nt * 16 + row) * Cn + kk);
        #pragma unroll
        for (int mt = 0; mt < 2; ++mt)
            #pragma unroll
            for (int nt = 0; nt < 4; ++nt)
                acc[mt][nt] = __builtin_amdgcn_mfma_f32_16x16x32_bf16(a[mt], bf[nt], acc[mt][nt], 0, 0, 0);
    }

    #pragma unroll
    for (int mt = 0; mt < 2; ++mt) {
        #pragma unroll
        for (int r = 0; r < 4; ++r) {
            int o = m0 + mt * 16 + quad * 4 + r;
            float sc = bsc[o], sh = bsh[o];
            #pragma unroll
            for (int nt = 0; nt < 4; ++nt) {
                float v = acc[mt][nt][r] * sc + sh;
                v = v > 0.f ? v : 0.f;
                out[(size_t)(bz * On + o) * HWn + n0 + nt * 16 + row] = v;
            }
        }
    }
}

extern "C" void kernel_launch(void* const* d_in, const int* in_sizes, int n_in,
                              void* d_out, int out_size, void* d_ws, size_t ws_size,
                              hipStream_t stream)
{
    const float* x     = (const float*)d_in[0];
    const float* gf    = (const float*)d_in[1];
    const float* off_w = (const float*)d_in[2];
    const float* og    = (const float*)d_in[3];
    const float* ob    = (const float*)d_in[4];
    const float* om    = (const float*)d_in[5];
    const float* ov    = (const float*)d_in[6];
    const float* dw_w  = (const float*)d_in[7];
    const float* pw_w  = (const float*)d_in[8];
    const float* bg    = (const float*)d_in[9];
    const float* bb    = (const float*)d_in[10];
    const float* bm    = (const float*)d_in[11];
    const float* bv    = (const float*)d_in[12];
    float* out = (float*)d_out;
    char* ws = (char*)d_ws;

    hipLaunchKernelGGL(k_tables, dim3(1), dim3(256), 0, stream,
                       off_w, og, ob, om, ov, dw_w, pw_w, bg, bb, bm, bv, ws);
    hipLaunchKernelGGL(k_tr, dim3(1024), dim3(256), 0, stream, x, ws);
    hipLaunchKernelGGL(k_off, dim3(Hn, Bn), dim3(512), 0, stream, gf, ws);
    hipLaunchKernelGGL(k_samp, dim3(Hn, Bn), dim3(512), 0, stream, ws);
    hipLaunchKernelGGL(k_pw, dim3(16, 8, Bn), dim3(256), 0, stream, out, ws);
}

// Round 3
// 187.247 us; speedup vs baseline: 1.4293x; 1.3013x over previous
//
#include <hip/hip_runtime.h>
#include <stdint.h>

#define Bn 4
#define Cn 256
#define On 256
#define Gn 64
#define Hn 64
#define Wn 64
#define HWn 4096
#define EPSf 1e-5f

// workspace byte offsets (16B-aligned)
#define WS_XT    0u               // x NHWC bf16: 8388608
#define WS_OFF   8388608u         // off [b][pos][18] f32: 1179648
#define WS_PWB   9768256u         // pw bf16 [o][c]: 131072   (9568256 rounded up)
#define WS_DWT   9899328u         // dw [k][c] f32: 9216
#define WS_OSC   9908544u
#define WS_OSH   9908672u
#define WS_BSC   9908800u
#define WS_BSH   9909824u
#define WS_WT    9910848u         // off_w [g][ty][56] f32: 43008

typedef __attribute__((ext_vector_type(8))) short short8;
typedef __attribute__((ext_vector_type(4))) float f4;

__device__ __forceinline__ unsigned int bfround(float f) {
    unsigned int u = __float_as_uint(f);
    u += 0x7FFFu + ((u >> 16) & 1u);
    return u >> 16;
}
__device__ __forceinline__ float blo(unsigned u) { return __uint_as_float(u << 16); }
__device__ __forceinline__ float bhi(unsigned u) { return __uint_as_float(u & 0xFFFF0000u); }

// ---------------- tables: 33 blocks (0..31 convert pw, 32 does misc) ----------------
__global__ void k_tables(const float* __restrict__ off_w,
                         const float* __restrict__ og, const float* __restrict__ ob,
                         const float* __restrict__ om, const float* __restrict__ ov,
                         const float* __restrict__ dw_w, const float* __restrict__ pw_w,
                         const float* __restrict__ bg, const float* __restrict__ bb,
                         const float* __restrict__ bm, const float* __restrict__ bv,
                         char* __restrict__ ws)
{
    int tid = threadIdx.x;
    if (blockIdx.x < 32) {
        // pw f32 -> bf16, 16384 float4 over 32 blocks
        unsigned short* pwb = (unsigned short*)(ws + WS_PWB);
        const float4* p4 = (const float4*)pw_w;
        uint2* o2 = (uint2*)pwb;
        int base = blockIdx.x * 512;
        #pragma unroll
        for (int i = 0; i < 2; ++i) {
            int idx = base + i * 256 + tid;
            float4 f = p4[idx];
            uint2 pk;
            pk.x = bfround(f.x) | (bfround(f.y) << 16);
            pk.y = bfround(f.z) | (bfround(f.w) << 16);
            o2[idx] = pk;
        }
        return;
    }
    float* dwt = (float*)(ws + WS_DWT);
    float* osc = (float*)(ws + WS_OSC);
    float* osh = (float*)(ws + WS_OSH);
    float* bsc = (float*)(ws + WS_BSC);
    float* bsh = (float*)(ws + WS_BSH);
    float* wT  = (float*)(ws + WS_WT);
    if (tid < 18) {
        float s = og[tid] * rsqrtf(ov[tid] + EPSf);
        osc[tid] = s;
        osh[tid] = ob[tid] - om[tid] * s;
    }
    {
        float s = bg[tid] * rsqrtf(bv[tid] + EPSf);
        bsc[tid] = s;
        bsh[tid] = bb[tid] - bm[tid] * s;
    }
    for (int idx = tid; idx < 2304; idx += 256) {
        int k = idx >> 8, c = idx & 255;
        dwt[idx] = dw_w[c * 9 + k];                     // dwt[k][c]
    }
    for (int i = tid; i < 10368; i += 256) {
        int ch = i % 18; int r = i / 18;
        int tx = r % 3; r /= 3; int ty = r % 3; int g = r / 3;
        wT[(g * 3 + ty) * 56 + tx * 18 + ch] = off_w[((ch * 64 + g) * 3 + ty) * 3 + tx];
    }
}

// ---------------- transpose x NCHW f32 -> NHWC bf16 ----------------
__global__ void k_tr(const float* __restrict__ x, char* __restrict__ ws)
{
    unsigned short* xt = (unsigned short*)(ws + WS_XT);
    __shared__ float tile[64 * 65];
    int tid = threadIdx.x, bi = blockIdx.x;
    int pt = bi & 63, ct = (bi >> 6) & 3, b = bi >> 8;
    int p0 = pt * 64, c0 = ct * 64;
    const float4* x4 = (const float4*)(x + (size_t)b * Cn * HWn);
    #pragma unroll
    for (int it = 0; it < 4; ++it) {
        int v = it * 256 + tid;
        int ci = v >> 4, pj = v & 15;
        float4 f = x4[(size_t)(c0 + ci) * 1024 + (p0 >> 2) + pj];
        tile[ci * 65 + pj * 4 + 0] = f.x;
        tile[ci * 65 + pj * 4 + 1] = f.y;
        tile[ci * 65 + pj * 4 + 2] = f.z;
        tile[ci * 65 + pj * 4 + 3] = f.w;
    }
    __syncthreads();
    unsigned short* xtb = xt + (size_t)b * HWn * Cn;
    #pragma unroll
    for (int it = 0; it < 2; ++it) {
        int u = it * 256 + tid;
        int pi = u >> 3, cj = u & 7;
        float f[8];
        #pragma unroll
        for (int j = 0; j < 8; ++j)
            f[j] = tile[(cj * 8 + j) * 65 + pi];
        uint4 pk;
        pk.x = bfround(f[0]) | (bfround(f[1]) << 16);
        pk.y = bfround(f[2]) | (bfround(f[3]) << 16);
        pk.z = bfround(f[4]) | (bfround(f[5]) << 16);
        pk.w = bfround(f[6]) | (bfround(f[7]) << 16);
        *(uint4*)(xtb + (size_t)(p0 + pi) * Cn + c0 + cj * 8) = pk;
    }
}

// ---------------- offset conv (G=64->18, 3x3, pad1) + BN + ReLU ----------------
__global__ void k_off(const float* __restrict__ gf, char* __restrict__ ws)
{
    const float* __restrict__ wT  = (const float*)(ws + WS_WT);
    const float* __restrict__ osc = (const float*)(ws + WS_OSC);
    const float* __restrict__ osh = (const float*)(ws + WS_OSH);
    float* __restrict__ off = (float*)(ws + WS_OFF);
    __shared__ float sgf[3 * 64 * 72];        // [ty][g][72]; data at [4..67]
    __shared__ float sred[8 * 18 * 64];       // [wv][ch][w]
    int h = blockIdx.x, b = blockIdx.y;
    int tid = threadIdx.x;
    int lane = tid & 63;

    const float4* gf4 = (const float4*)gf;
    #pragma unroll
    for (int i = 0; i < 6; ++i) {
        int idx = i * 512 + tid;
        int r = idx >> 4, pj = idx & 15;
        int ty = r >> 6, g = r & 63;
        int y = h + ty - 1;
        float4 v = {0.f, 0.f, 0.f, 0.f};
        if ((unsigned)y < 64u)
            v = gf4[((size_t)(b * 64 + g) * 64 + y) * 16 + pj];
        *(float4*)(&sgf[r * 72 + 4 + pj * 4]) = v;
    }
    if (tid < 192) {
        sgf[tid * 72 + 3] = 0.f;
        sgf[tid * 72 + 68] = 0.f;
    }
    __syncthreads();

    int wvU = __builtin_amdgcn_readfirstlane(tid >> 6);
    float acc[18];
    #pragma unroll
    for (int ch = 0; ch < 18; ++ch) acc[ch] = 0.f;

    for (int gi = 0; gi < 8; ++gi) {
        int g = wvU * 8 + gi;
        #pragma unroll
        for (int ty = 0; ty < 3; ++ty) {
            const float* row = &sgf[(ty * 64 + g) * 72];
            float v0 = row[3 + lane];
            float v1 = row[4 + lane];
            float v2 = row[5 + lane];
            const float* wrow = wT + (g * 3 + ty) * 56;   // uniform -> s_load
            #pragma unroll
            for (int ch = 0; ch < 18; ++ch)
                acc[ch] += wrow[ch] * v0 + wrow[18 + ch] * v1 + wrow[36 + ch] * v2;
        }
    }
    #pragma unroll
    for (int ch = 0; ch < 18; ++ch)
        sred[(wvU * 18 + ch) * 64 + lane] = acc[ch];
    __syncthreads();

    float* ob = off + (size_t)(b * HWn + h * 64) * 18;
    for (int idx = tid; idx < 1152; idx += 512) {
        int w = idx / 18, ch = idx - w * 18;
        float v = 0.f;
        #pragma unroll
        for (int wv = 0; wv < 8; ++wv)
            v += sred[(wv * 18 + ch) * 64 + w];
        v = v * osc[ch] + osh[ch];
        ob[idx] = v > 0.f ? v : 0.f;
    }
}

// ---------------- fused: bilinear gather + depthwise -> LDS, MFMA pointwise + BN + ReLU ----------------
// grid 256 blocks x 512 threads. XCD swizzle: each XCD pair-slot serves one batch.
#define TLD 264   // t-tile row stride in shorts (256 + 8 pad)
__global__ void k_fuse(float* __restrict__ out, const char* __restrict__ ws)
{
    const unsigned short* __restrict__ xt  = (const unsigned short*)(ws + WS_XT);
    const unsigned short* __restrict__ pwb = (const unsigned short*)(ws + WS_PWB);
    const float* __restrict__ off = (const float*)(ws + WS_OFF);
    const float* __restrict__ dwt = (const float*)(ws + WS_DWT);
    const float* __restrict__ bsc = (const float*)(ws + WS_BSC);
    const float* __restrict__ bsh = (const float*)(ws + WS_BSH);
    __shared__ float smeta[576 * 8];          // [(k*64+w)]: 4 weights + 4 byte-offsets
    __shared__ unsigned short tl[64 * TLD];   // t tile [pos][ch], padded

    int bid = blockIdx.x;
    int xcd = bid & 7;
    int b = xcd >> 1;                         // XCDs {0,1}->b0, {2,3}->b1, ...
    int h = ((bid >> 3) << 1) | (xcd & 1);
    int tid = threadIdx.x;

    // ---- phase 1: per-(w,k) bilinear meta ----
    for (int e = tid; e < 576; e += 512) {
        int k = e >> 6, w = e & 63;
        int kyi = k / 3, kxi = k - kyi * 3;
        const float* op = off + ((size_t)(b * HWn + h * 64 + w)) * 18 + 2 * k;
        float dy = op[0], dx = op[1];
        float gy = (float)(h + (kyi - 1) * 2) + dy;
        float gx = (float)(w + (kxi - 1) * 2) + dx;
        float fy = floorf(gy), fx = floorf(gx);
        float wy = gy - fy, wx = gx - fx;
        int y0 = (int)fy, x0 = (int)fx;
        int y1 = y0 + 1, x1 = x0 + 1;
        float m00 = ((unsigned)y0 < 64u && (unsigned)x0 < 64u) ? 1.f : 0.f;
        float m01 = ((unsigned)y0 < 64u && (unsigned)x1 < 64u) ? 1.f : 0.f;
        float m10 = ((unsigned)y1 < 64u && (unsigned)x0 < 64u) ? 1.f : 0.f;
        float m11 = ((unsigned)y1 < 64u && (unsigned)x1 < 64u) ? 1.f : 0.f;
        int y0c = min(max(y0, 0), 63), y1c = min(max(y1, 0), 63);
        int x0c = min(max(x0, 0), 63), x1c = min(max(x1, 0), 63);
        float4 mw;
        mw.x = (1.f - wy) * (1.f - wx) * m00;
        mw.y = (1.f - wy) * wx * m01;
        mw.z = wy * (1.f - wx) * m10;
        mw.w = wy * wx * m11;
        float4 mo;
        mo.x = __int_as_float((y0c * 64 + x0c) << 9);   // *256ch *2B
        mo.y = __int_as_float((y0c * 64 + x1c) << 9);
        mo.z = __int_as_float((y1c * 64 + x0c) << 9);
        mo.w = __int_as_float((y1c * 64 + x1c) << 9);
        float4* s4w = (float4*)smeta;
        s4w[(k * 64 + w) * 2] = mw;
        s4w[(k * 64 + w) * 2 + 1] = mo;
    }

    int lane = tid & 63, wave = tid >> 6;
    int half = lane >> 5, c8 = lane & 31;
    int c0 = c8 * 8;
    float dwr[9][8];
    #pragma unroll
    for (int k = 0; k < 9; ++k) {
        *(float4*)&dwr[k][0] = *(const float4*)(dwt + k * 256 + c0);
        *(float4*)&dwr[k][4] = *(const float4*)(dwt + k * 256 + c0 + 4);
    }
    __syncthreads();

    // ---- phase 2: gather + depthwise -> LDS t tile ----
    const char* xb = (const char*)(xt + (size_t)b * HWn * Cn);
    int laneByte = c8 * 16;
    const float4* s4 = (const float4*)smeta;
    #pragma unroll
    for (int iter = 0; iter < 4; ++iter) {
        int w = iter * 16 + wave * 2 + half;
        float acc[8];
        #pragma unroll
        for (int j = 0; j < 8; ++j) acc[j] = 0.f;
        #pragma unroll
        for (int k = 0; k < 9; ++k) {
            float4 mw = s4[(k * 64 + w) * 2];
            float4 mo = s4[(k * 64 + w) * 2 + 1];
            uint4 qA = *(const uint4*)(xb + __float_as_int(mo.x) + laneByte);
            uint4 qB = *(const uint4*)(xb + __float_as_int(mo.y) + laneByte);
            uint4 qC = *(const uint4*)(xb + __float_as_int(mo.z) + laneByte);
            uint4 qD = *(const uint4*)(xb + __float_as_int(mo.w) + laneByte);
            const unsigned* uA = (const unsigned*)&qA;
            const unsigned* uB = (const unsigned*)&qB;
            const unsigned* uC = (const unsigned*)&qC;
            const unsigned* uD = (const unsigned*)&qD;
            #pragma unroll
            for (int j = 0; j < 4; ++j) {
                float sl = mw.x * blo(uA[j]) + mw.y * blo(uB[j]) + mw.z * blo(uC[j]) + mw.w * blo(uD[j]);
                float sh = mw.x * bhi(uA[j]) + mw.y * bhi(uB[j]) + mw.z * bhi(uC[j]) + mw.w * bhi(uD[j]);
                acc[2 * j]     += sl * dwr[k][2 * j];
                acc[2 * j + 1] += sh * dwr[k][2 * j + 1];
            }
        }
        uint4 pk;
        pk.x = bfround(acc[0]) | (bfround(acc[1]) << 16);
        pk.y = bfround(acc[2]) | (bfround(acc[3]) << 16);
        pk.z = bfround(acc[4]) | (bfround(acc[5]) << 16);
        pk.w = bfround(acc[6]) | (bfround(acc[7]) << 16);
        *(uint4*)(&tl[w * TLD + c0]) = pk;
    }
    __syncthreads();

    // ---- phase 3: 256x64x256 MFMA vs pw + BN + ReLU ----
    int m0 = wave * 32;                       // 8 waves x 32 o = 256
    int row = lane & 15, quad = lane >> 4;
    f4 acc[2][4];
    #pragma unroll
    for (int i = 0; i < 2; ++i)
        #pragma unroll
        for (int j = 0; j < 4; ++j)
            acc[i][j] = (f4){0.f, 0.f, 0.f, 0.f};

    #pragma unroll 2
    for (int kq = 0; kq < 8; ++kq) {
        int kk = kq * 32 + quad * 8;
        short8 a[2], bf[4];
        #pragma unroll
        for (int mt = 0; mt < 2; ++mt)
            a[mt] = *(const short8*)(pwb + (size_t)(m0 + mt * 16 + row) * Cn + kk);
        #pragma unroll
        for (int nt = 0; nt < 4; ++nt)
            bf[nt] = *(const short8*)(&tl[(nt * 16 + row) * TLD + kk]);
        #pragma unroll
        for (int mt = 0; mt < 2; ++mt)
            #pragma unroll
            for (int nt = 0; nt < 4; ++nt)
                acc[mt][nt] = __builtin_amdgcn_mfma_f32_16x16x32_bf16(a[mt], bf[nt], acc[mt][nt], 0, 0, 0);
    }

    float* ob = out + (size_t)b * On * HWn + h * 64;
    #pragma unroll
    for (int mt = 0; mt < 2; ++mt) {
        #pragma unroll
        for (int r = 0; r < 4; ++r) {
            int o = m0 + mt * 16 + quad * 4 + r;
            float sc = bsc[o], sh = bsh[o];
            #pragma unroll
            for (int nt = 0; nt < 4; ++nt) {
                float v = acc[mt][nt][r] * sc + sh;
                v = v > 0.f ? v : 0.f;
                ob[(size_t)o * HWn + nt * 16 + row] = v;
            }
        }
    }
}

extern "C" void kernel_launch(void* const* d_in, const int* in_sizes, int n_in,
                              void* d_out, int out_size, void* d_ws, size_t ws_size,
                              hipStream_t stream)
{
    const float* x     = (const float*)d_in[0];
    const float* gf    = (const float*)d_in[1];
    const float* off_w = (const float*)d_in[2];
    const float* og    = (const float*)d_in[3];
    const float* ob    = (const float*)d_in[4];
    const float* om    = (const float*)d_in[5];
    const float* ov    = (const float*)d_in[6];
    const float* dw_w  = (const float*)d_in[7];
    const float* pw_w  = (const float*)d_in[8];
    const float* bg    = (const float*)d_in[9];
    const float* bb    = (const float*)d_in[10];
    const float* bm    = (const float*)d_in[11];
    const float* bv    = (const float*)d_in[12];
    float* out = (float*)d_out;
    char* ws = (char*)d_ws;

    hipLaunchKernelGGL(k_tables, dim3(33), dim3(256), 0, stream,
                       off_w, og, ob, om, ov, dw_w, pw_w, bg, bb, bm, bv, ws);
    hipLaunchKernelGGL(k_tr, dim3(1024), dim3(256), 0, stream, x, ws);
    hipLaunchKernelGGL(k_off, dim3(Hn, Bn), dim3(512), 0, stream, gf, ws);
    hipLaunchKernelGGL(k_fuse, dim3(256), dim3(512), 0, stream, out, ws);
}